// Round 1
// baseline (17524.455 us; speedup 1.0000x reference)
//
#include <hip/hip_runtime.h>
#include <hip/hip_bf16.h>
#include <math.h>

#define Lnum 4
#define Hn 8
#define Cc 512
#define Tt 2048
#define Vv 50257
#define HDim 64
#define FF 2048
#define BT 4096   // B*T rows

#define GF_RESID 1
#define GF_RELU  2

__device__ inline float waveReduceSum(float v) {
    for (int o = 32; o; o >>= 1) v += __shfl_down(v, o, 64);
    return v;
}
__device__ inline float waveReduceMax(float v) {
    for (int o = 32; o; o >>= 1) v = fmaxf(v, __shfl_down(v, o, 64));
    return v;
}

// -------------------- embedding --------------------
__global__ __launch_bounds__(256) void embed_k(const int* __restrict__ xi,
                                               const float* __restrict__ tok,
                                               const float* __restrict__ pos,
                                               float* __restrict__ h) {
    int idx = blockIdx.x * 256 + threadIdx.x;   // BT*C total
    int row = idx >> 9;        // /512
    int c = idx & 511;
    int t = row & (Tt - 1);
    int token = xi[row];
    h[idx] = tok[(size_t)token * Cc + c] + pos[(size_t)t * Cc + c];
}

// -------------------- layernorm (row of 512) --------------------
__global__ __launch_bounds__(256) void ln_k(const float* __restrict__ x,
                                            const float* __restrict__ g,
                                            const float* __restrict__ b,
                                            float* __restrict__ o) {
    __shared__ float redA[8];
    int row = blockIdx.x;
    int tid = threadIdx.x, lane = tid & 63, w = tid >> 6;
    const float* xr = x + (size_t)row * Cc;
    float v0 = xr[tid], v1 = xr[tid + 256];
    float s = v0 + v1, sq = v0 * v0 + v1 * v1;
    s = waveReduceSum(s);
    sq = waveReduceSum(sq);
    if (lane == 0) { redA[w] = s; redA[4 + w] = sq; }
    __syncthreads();
    if (tid == 0) {
        redA[0] = redA[0] + redA[1] + redA[2] + redA[3];
        redA[4] = redA[4] + redA[5] + redA[6] + redA[7];
    }
    __syncthreads();
    float mean = redA[0] * (1.0f / Cc);
    float var = redA[4] * (1.0f / Cc) - mean * mean;
    float rstd = rsqrtf(var + 1e-5f);
    float* orow = o + (size_t)row * Cc;
    orow[tid]       = (v0 - mean) * rstd * g[tid]       + b[tid];
    orow[tid + 256] = (v1 - mean) * rstd * g[tid + 256] + b[tid + 256];
}

// -------------------- generic tiled GEMM --------------------
// C[M,N] = A[M,K] @ W' (+bias) (+relu) (+residual into C)
// W'[c,n] = W[(size_t)c*w_ldk + (n>>hd_shift)*w_ldh + (n & ((1<<hd_shift)-1))]
// M % 64 == 0, K % 16 == 0; N arbitrary (bounds-checked).
__global__ __launch_bounds__(256) void gemm_k(const float* __restrict__ A,
                                              const float* __restrict__ W,
                                              const float* __restrict__ bias,
                                              float* __restrict__ Cmat,
                                              int M, int N, int K,
                                              int w_ldk, int w_ldh, int hd_shift,
                                              int flags) {
    __shared__ __align__(16) float As[16][64];
    __shared__ __align__(16) float Bs[16][64];
    int tid = threadIdx.x;
    int tr = tid >> 4, tc = tid & 15;
    int row0 = blockIdx.y * 64;
    int col0 = blockIdx.x * 64;

    int aE = tid * 4;
    int am = aE >> 4;       // 0..63
    int ak = aE & 15;       // 0,4,8,12
    int bE = tid * 4;
    int bk = bE >> 6;       // 0..15
    int bn = bE & 63;
    unsigned mask = (1u << hd_shift) - 1u;

    float acc[4][4] = {{0.f}};

    for (int kk = 0; kk < K; kk += 16) {
        float4 av = *(const float4*)(A + (size_t)(row0 + am) * K + kk + ak);
        As[ak + 0][am] = av.x;
        As[ak + 1][am] = av.y;
        As[ak + 2][am] = av.z;
        As[ak + 3][am] = av.w;
#pragma unroll
        for (int i = 0; i < 4; i++) {
            int col = col0 + bn + i;
            float bvv = 0.f;
            if (col < N)
                bvv = W[(size_t)(kk + bk) * w_ldk +
                        (size_t)(col >> hd_shift) * w_ldh + (col & mask)];
            Bs[bk][bn + i] = bvv;
        }
        __syncthreads();
#pragma unroll
        for (int k2 = 0; k2 < 16; k2++) {
            float4 a4 = *(const float4*)&As[k2][tr * 4];
            float4 b4 = *(const float4*)&Bs[k2][tc * 4];
            acc[0][0] += a4.x * b4.x; acc[0][1] += a4.x * b4.y;
            acc[0][2] += a4.x * b4.z; acc[0][3] += a4.x * b4.w;
            acc[1][0] += a4.y * b4.x; acc[1][1] += a4.y * b4.y;
            acc[1][2] += a4.y * b4.z; acc[1][3] += a4.y * b4.w;
            acc[2][0] += a4.z * b4.x; acc[2][1] += a4.z * b4.y;
            acc[2][2] += a4.z * b4.z; acc[2][3] += a4.z * b4.w;
            acc[3][0] += a4.w * b4.x; acc[3][1] += a4.w * b4.y;
            acc[3][2] += a4.w * b4.z; acc[3][3] += a4.w * b4.w;
        }
        __syncthreads();
    }

#pragma unroll
    for (int i = 0; i < 4; i++) {
#pragma unroll
        for (int j = 0; j < 4; j++) {
            int col = col0 + tc * 4 + j;
            if (col < N) {
                size_t idx = (size_t)(row0 + tr * 4 + i) * N + col;
                float vv = acc[i][j];
                if (bias) vv += bias[col];
                if (flags & GF_RELU) vv = fmaxf(vv, 0.f);
                if (flags & GF_RESID) vv += Cmat[idx];
                Cmat[idx] = vv;
            }
        }
    }
}

// -------------------- causal attention, one (b,h,tq) per block --------------------
__global__ __launch_bounds__(256) void attn_k(const float* __restrict__ q,
                                              const float* __restrict__ k,
                                              const float* __restrict__ v,
                                              float* __restrict__ out) {
    __shared__ float sc[Tt];
    __shared__ float qs[HDim];
    __shared__ float pacc[256];
    __shared__ float redA[4];
    __shared__ float fin[2];
    int tq = blockIdx.x;
    int bh = blockIdx.y;
    int b = bh >> 3, h = bh & 7;
    int tid = threadIdx.x, lane = tid & 63, w = tid >> 6;
    size_t base = (size_t)b * Tt * Cc + (size_t)h * HDim;
    if (tid < HDim) qs[tid] = q[base + (size_t)tq * Cc + tid] * 0.125f;
    __syncthreads();
    // scores
    for (int s = w; s <= tq; s += 4) {
        float val = qs[lane] * k[base + (size_t)s * Cc + lane];
        val = waveReduceSum(val);
        if (lane == 0) sc[s] = val;
    }
    __syncthreads();
    // max
    float m = -3.0e38f;
    for (int i = tid; i <= tq; i += 256) m = fmaxf(m, sc[i]);
    m = waveReduceMax(m);
    if (lane == 0) redA[w] = m;
    __syncthreads();
    if (tid == 0) fin[0] = fmaxf(fmaxf(redA[0], redA[1]), fmaxf(redA[2], redA[3]));
    __syncthreads();
    m = fin[0];
    // sum of exp
    float sum = 0.f;
    for (int i = tid; i <= tq; i += 256) {
        float e = __expf(sc[i] - m);
        sc[i] = e;
        sum += e;
    }
    sum = waveReduceSum(sum);
    if (lane == 0) redA[w] = sum;
    __syncthreads();
    if (tid == 0) fin[1] = redA[0] + redA[1] + redA[2] + redA[3];
    __syncthreads();
    float inv = 1.0f / fin[1];
    // P @ V
    float acc = 0.f;
    for (int s = w; s <= tq; s += 4)
        acc += sc[s] * v[base + (size_t)s * Cc + lane];
    pacc[tid] = acc;
    __syncthreads();
    if (w == 0) {
        float r = pacc[lane] + pacc[64 + lane] + pacc[128 + lane] + pacc[192 + lane];
        out[base + (size_t)tq * Cc + lane] = r * inv;
    }
}

// -------------------- per-row loss term --------------------
__global__ __launch_bounds__(256) void lse_k(const float* __restrict__ logits,
                                             const int* __restrict__ tgt,
                                             float* __restrict__ rowloss) {
    __shared__ float redA[4];
    __shared__ float fin[2];
    int r = blockIdx.x;
    int tid = threadIdx.x, lane = tid & 63, w = tid >> 6;
    const float* p = logits + (size_t)r * Vv;
    float m = -3.0e38f;
    for (int i = tid; i < Vv; i += 256) m = fmaxf(m, p[i]);
    m = waveReduceMax(m);
    if (lane == 0) redA[w] = m;
    __syncthreads();
    if (tid == 0) fin[0] = fmaxf(fmaxf(redA[0], redA[1]), fmaxf(redA[2], redA[3]));
    __syncthreads();
    float bm = fin[0];
    float sum = 0.f;
    for (int i = tid; i < Vv; i += 256) sum += __expf(p[i] - bm);
    sum = waveReduceSum(sum);
    if (lane == 0) redA[w] = sum;
    __syncthreads();
    if (tid == 0) fin[1] = redA[0] + redA[1] + redA[2] + redA[3];
    __syncthreads();
    if (tid == 0) rowloss[r] = p[tgt[r]] - bm - logf(fin[1]);
}

__global__ __launch_bounds__(256) void loss_k(const float* __restrict__ rowloss,
                                              float* __restrict__ out) {
    __shared__ float redA[4];
    int tid = threadIdx.x, lane = tid & 63, w = tid >> 6;
    float s = 0.f;
    for (int i = tid; i < BT; i += 256) s += rowloss[i];
    s = waveReduceSum(s);
    if (lane == 0) redA[w] = s;
    __syncthreads();
    if (tid == 0) out[0] = -(redA[0] + redA[1] + redA[2] + redA[3]) * (1.0f / BT);
}

extern "C" void kernel_launch(void* const* d_in, const int* in_sizes, int n_in,
                              void* d_out, int out_size, void* d_ws, size_t ws_size,
                              hipStream_t stream) {
    const int*   x     = (const int*)d_in[0];
    const int*   tgt   = (const int*)d_in[1];
    const float* tok   = (const float*)d_in[2];
    const float* pos   = (const float*)d_in[3];
    const float* ln1s  = (const float*)d_in[4];
    const float* ln1b  = (const float*)d_in[5];
    const float* wq    = (const float*)d_in[6];
    const float* wk    = (const float*)d_in[7];
    const float* wv    = (const float*)d_in[8];
    const float* wproj = (const float*)d_in[9];
    const float* bproj = (const float*)d_in[10];
    const float* ln2s  = (const float*)d_in[11];
    const float* ln2b  = (const float*)d_in[12];
    const float* wff1  = (const float*)d_in[13];
    const float* bff1  = (const float*)d_in[14];
    const float* wff2  = (const float*)d_in[15];
    const float* bff2  = (const float*)d_in[16];
    const float* lnfs  = (const float*)d_in[17];
    const float* lnfb  = (const float*)d_in[18];
    const float* lmw   = (const float*)d_in[19];
    const float* lmb   = (const float*)d_in[20];

    const size_t rowsC = (size_t)BT * Cc;       // 2,097,152
    float* ws = (float*)d_ws;
    float* h   = ws;
    float* a   = h + rowsC;
    float* qb  = a + rowsC;
    float* kb  = qb + rowsC;
    float* vb  = kb + rowsC;
    float* mid = vb + rowsC;                    // BT*FF
    float* rowloss = mid + (size_t)BT * FF;
    // total floats: 5*rowsC + BT*FF + BT = 18,878,464 (~75.5 MB)
    if (ws_size < (5 * rowsC + (size_t)BT * FF + BT) * sizeof(float)) return;

    float* logits = (float*)d_out;
    float* lossp = logits + (size_t)BT * Vv;

    embed_k<<<(BT * Cc) / 256, 256, 0, stream>>>(x, tok, pos, h);

    dim3 g512(Cc / 64, BT / 64);
    dim3 gff1(FF / 64, BT / 64);
    dim3 gattn(Tt, 2 * Hn);

    for (int l = 0; l < Lnum; l++) {
        const float* wq_l = wq + (size_t)l * Hn * Cc * HDim;
        const float* wk_l = wk + (size_t)l * Hn * Cc * HDim;
        const float* wv_l = wv + (size_t)l * Hn * Cc * HDim;
        ln_k<<<BT, 256, 0, stream>>>(h, ln1s + l * Cc, ln1b + l * Cc, a);
        // q/k/v into [B,T,C] layout with head-blocked weight indexing
        gemm_k<<<g512, 256, 0, stream>>>(a, wq_l, nullptr, qb, BT, Cc, Cc,
                                         HDim, Cc * HDim, 6, 0);
        gemm_k<<<g512, 256, 0, stream>>>(a, wk_l, nullptr, kb, BT, Cc, Cc,
                                         HDim, Cc * HDim, 6, 0);
        gemm_k<<<g512, 256, 0, stream>>>(a, wv_l, nullptr, vb, BT, Cc, Cc,
                                         HDim, Cc * HDim, 6, 0);
        attn_k<<<gattn, 256, 0, stream>>>(qb, kb, vb, a);
        gemm_k<<<g512, 256, 0, stream>>>(a, wproj + (size_t)l * Cc * Cc,
                                         bproj + l * Cc, h, BT, Cc, Cc,
                                         Cc, 0, 30, GF_RESID);
        ln_k<<<BT, 256, 0, stream>>>(h, ln2s + l * Cc, ln2b + l * Cc, a);
        gemm_k<<<gff1, 256, 0, stream>>>(a, wff1 + (size_t)l * Cc * FF,
                                         bff1 + l * FF, mid, BT, FF, Cc,
                                         FF, 0, 30, GF_RELU);
        gemm_k<<<g512, 256, 0, stream>>>(mid, wff2 + (size_t)l * FF * Cc,
                                         bff2 + l * Cc, h, BT, Cc, FF,
                                         Cc, 0, 30, GF_RESID);
    }

    ln_k<<<BT, 256, 0, stream>>>(h, lnfs, lnfb, a);
    dim3 glog((Vv + 63) / 64, BT / 64);
    gemm_k<<<glog, 256, 0, stream>>>(a, lmw, lmb, logits, BT, Vv, Cc,
                                     Vv, 0, 30, 0);
    lse_k<<<BT, 256, 0, stream>>>(logits, tgt, rowloss);
    loss_k<<<1, 256, 0, stream>>>(rowloss, lossp);
}